// Round 8
// baseline (842.794 us; speedup 1.0000x reference)
//
#include <hip/hip_runtime.h>
#include <cstdint>

#define SEQ    2048
#define DM     512
#define DAUX   64

typedef _Float16 f16;
typedef __attribute__((ext_vector_type(2))) _Float16 f16x2;
typedef __attribute__((ext_vector_type(4))) _Float16 f16x4;
typedef __attribute__((ext_vector_type(8))) _Float16 f16x8;
typedef __attribute__((ext_vector_type(16))) float fx16;

#define MFMA32(a, b, c) __builtin_amdgcn_mfma_f32_32x32x16_f16(a, b, c, 0, 0, 0)

// ---------------------------------------------------------------------------
// All-register 3-pass split GEMM over K=512 (16 chunks of BK=32).
// Fragments loaded straight from global (L1/L2) as 16B dwordx4 per lane:
// A/B lane map [m=lane&31][k=(lane>>5)*8 + j] -> 16B contiguous in k.
// One-chunk-deep register ping-pong; no LDS, no barriers, no vmcnt drains.
// Pointers are pre-offset per lane: base + (row+r31)*stride + half8.
// NOTE: final iteration prefetches k=512 (reads a few KB past the logical
// array into the adjacent ws buffer — mapped, unused).
// ---------------------------------------------------------------------------
__device__ __forceinline__ void gemm3_regs(
    const f16* __restrict__ Ah, const f16* __restrict__ Al,
    const f16* __restrict__ Bh, const f16* __restrict__ Bl,
    fx16 acc[2][2]) {
  f16x8 fah[2][2][2], fal[2][2][2], fbh[2][2][2], fbl[2][2][2]; // [buf][it][k]
  auto load3 = [&](int buf, int kb) {
#pragma unroll
    for (int i2 = 0; i2 < 2; ++i2)
#pragma unroll
      for (int k2 = 0; k2 < 2; ++k2) {
        fah[buf][i2][k2] = *(const f16x8*)(Ah + (size_t)i2 * 32 * DM + kb + k2 * 16);
        fal[buf][i2][k2] = *(const f16x8*)(Al + (size_t)i2 * 32 * DM + kb + k2 * 16);
        fbh[buf][i2][k2] = *(const f16x8*)(Bh + (size_t)i2 * 32 * DM + kb + k2 * 16);
        fbl[buf][i2][k2] = *(const f16x8*)(Bl + (size_t)i2 * 32 * DM + kb + k2 * 16);
      }
  };
  load3(0, 0);
#pragma unroll 2
  for (int c = 0; c < 16; ++c) {
    int cur = c & 1, nxt = cur ^ 1;
    load3(nxt, (c + 1) * 32);           // prefetch next chunk into other buffer
#pragma unroll
    for (int k = 0; k < 2; ++k)
#pragma unroll
      for (int jt = 0; jt < 2; ++jt)
#pragma unroll
        for (int it = 0; it < 2; ++it) {
          acc[it][jt] = MFMA32(fah[cur][it][k], fbh[cur][jt][k], acc[it][jt]);
          acc[it][jt] = MFMA32(fah[cur][it][k], fbl[cur][jt][k], acc[it][jt]);
          acc[it][jt] = MFMA32(fal[cur][it][k], fbh[cur][jt][k], acc[it][jt]);
        }
  }
}

// All-register 1-pass GEMM, BK=64 chunks, NCH chunks, row strides SA/SB (f16).
template <int NCH, int SA, int SB>
__device__ __forceinline__ void gemm1_regs(
    const f16* __restrict__ A, const f16* __restrict__ B, fx16 acc[2][2]) {
  f16x8 fa[2][2][4], fb[2][2][4];     // [buf][it][k]
  auto load1 = [&](int buf, int kb) {
#pragma unroll
    for (int i2 = 0; i2 < 2; ++i2)
#pragma unroll
      for (int k2 = 0; k2 < 4; ++k2) {
        fa[buf][i2][k2] = *(const f16x8*)(A + (size_t)i2 * 32 * SA + kb + k2 * 16);
        fb[buf][i2][k2] = *(const f16x8*)(B + (size_t)i2 * 32 * SB + kb + k2 * 16);
      }
  };
  load1(0, 0);
#pragma unroll 2
  for (int c = 0; c < NCH; ++c) {
    int cur = c & 1, nxt = cur ^ 1;
    load1(nxt, (c + 1) * 64);
#pragma unroll
    for (int k = 0; k < 4; ++k)
#pragma unroll
      for (int jt = 0; jt < 2; ++jt)
#pragma unroll
        for (int it = 0; it < 2; ++it)
          acc[it][jt] = MFMA32(fa[cur][it][k], fb[cur][jt][k], acc[it][jt]);
  }
}

// ---------------------------------------------------------------------------
// Convert: x and Wq/Wk/Wv -> scaled split f16 (v*32 = hi + lo).
// ---------------------------------------------------------------------------
__global__ __launch_bounds__(256) void convert_split(
    const float* __restrict__ x, const float* __restrict__ Wq,
    const float* __restrict__ Wk, const float* __restrict__ Wv,
    f16* __restrict__ xh, f16* __restrict__ xl,
    f16* __restrict__ Wh, f16* __restrict__ Wl) {
  int idx = blockIdx.x * 256 + threadIdx.x;   // float4 index, 0..2293759
  const float* src; f16* dh; f16* dl; size_t off;
  if (idx < 2097152) { src = x; off = (size_t)idx; dh = xh; dl = xl; }
  else {
    int rr = idx - 2097152;
    int w = rr >> 16, o = rr & 65535;
    src = (w == 0) ? Wq : (w == 1) ? Wk : Wv;
    off = (size_t)o;
    dh = Wh + (size_t)w * 262144; dl = Wl + (size_t)w * 262144;
  }
  float4 v = ((const float4*)src)[off];
  float vv[4] = {v.x, v.y, v.z, v.w};
  f16x4 hv, lv;
#pragma unroll
  for (int i = 0; i < 4; ++i) {
    float s = vv[i] * 32.0f;
    f16 hi = (f16)s;
    hv[i] = hi;
    lv[i] = (f16)(s - (float)hi);
  }
  *(f16x4*)(dh + off * 4) = hv;
  *(f16x4*)(dl + off * 4) = lv;
}

// ---------------------------------------------------------------------------
// QKV: C = x*W^T + b. z=0 -> q split (3-pass); z=1 -> k split (3-pass);
// z=2 -> v single f16 TRANSPOSED (1-pass). All-register, no LDS.
// ---------------------------------------------------------------------------
__global__ __launch_bounds__(256, 2) void qkv_mfma(
    const f16* __restrict__ xh, const f16* __restrict__ xl,
    const f16* __restrict__ Wh, const f16* __restrict__ Wl,
    const float* __restrict__ bq, const float* __restrict__ bk, const float* __restrict__ bv,
    f16* __restrict__ qh, f16* __restrict__ ql,
    f16* __restrict__ kh, f16* __restrict__ kl,
    f16* __restrict__ vt) {
  const int t = threadIdx.x;
  const int i0 = blockIdx.x * 128, j0 = blockIdx.y * 128, z = blockIdx.z;
  const f16* WhZ = Wh + (size_t)z * 262144;
  const f16* WlZ = Wl + (size_t)z * 262144;
  const int lane = t & 63, wave = t >> 6;
  const int wm = wave >> 1, wn = wave & 1;
  const int r31 = lane & 31, half = lane >> 5;
  const int half8 = half * 8;
  fx16 acc[2][2] = {};
  const size_t arow = (size_t)(i0 + wm * 64 + r31);
  const size_t brow = (size_t)(j0 + wn * 64 + r31);
  if (z < 2) {
    gemm3_regs(xh + arow * DM + half8, xl + arow * DM + half8,
               WhZ + brow * DM + half8, WlZ + brow * DM + half8, acc);
  } else {
    gemm1_regs<8, DM, DM>(xh + arow * DM + half8, WhZ + brow * DM + half8, acc);
  }
  const float* bias = (z == 0) ? bq : (z == 1) ? bk : bv;
  if (z < 2) {
    f16* oh = z ? kh : qh;  f16* ol = z ? kl : ql;
#pragma unroll
    for (int it = 0; it < 2; ++it)
#pragma unroll
      for (int jt = 0; jt < 2; ++jt) {
        int j = j0 + wn * 64 + jt * 32 + r31;
        float bj = bias[j];
#pragma unroll
        for (int r = 0; r < 16; ++r) {
          int ib = i0 + wm * 64 + it * 32 + (r & 3) + 8 * (r >> 2) + 4 * half;
          float val = acc[it][jt][r] * (1.0f / 1024.0f) + bj;   // exact f32 value
          float s = val * 32.0f;                                 // re-split, scaled
          f16 hi = (f16)s;
          oh[(size_t)ib * DM + j] = hi;
          ol[(size_t)ib * DM + j] = (f16)(s - (float)hi);
        }
      }
  } else {
#pragma unroll
    for (int it = 0; it < 2; ++it)
#pragma unroll
      for (int jt = 0; jt < 2; ++jt) {
        int j = j0 + wn * 64 + jt * 32 + r31;
        float bj = bias[j];
#pragma unroll
        for (int q4 = 0; q4 < 4; ++q4) {
          int ib = i0 + wm * 64 + it * 32 + 8 * q4 + 4 * half;   // 4 consecutive rows
          int bb = ib >> 11, nb = ib & 2047;
          f16x4 hv;
#pragma unroll
          for (int g = 0; g < 4; ++g)
            hv[g] = (f16)(acc[it][jt][q4 * 4 + g] * (1.0f / 1024.0f) + bj);
          *(f16x4*)(vt + ((size_t)(bb * DM + j)) * SEQ + nb) = hv;
        }
      }
  }
}

// ---------------------------------------------------------------------------
// Scores: aux first (all-register, packed to f16 sax -> 16 VGPRs), then
// 3-pass split QK^T (f32-faithful at the threshold compare), merge+mask,
// store S f16. No LDS, no barriers.
// ---------------------------------------------------------------------------
__global__ __launch_bounds__(256, 2) void scores_mfma(
    const f16* __restrict__ qh, const f16* __restrict__ ql,
    const f16* __restrict__ kh, const f16* __restrict__ kl,
    const float* __restrict__ qa, const float* __restrict__ ka,
    const int* __restrict__ adj,
    const float* __restrict__ mc_p, const float* __restrict__ thr_p,
    f16* __restrict__ S16) {
  const int t = threadIdx.x;
  const int n0 = blockIdx.x * 128, m0 = blockIdx.y * 128, b = blockIdx.z;
  const int lane = t & 63, wave = t >> 6;
  const int wm = wave >> 1, wn = wave & 1;
  const int r31 = lane & 31, half = lane >> 5;
  const int half8 = half * 8;

  // ---- aux phase: f32 loads -> f16 frags in VALU, K=64 ----
  f16x2 sax2[2][2][8];
  {
    fx16 aacc[2][2] = {};
    const float* QAp = qa + ((size_t)b * SEQ + n0 + wm * 64 + r31) * DAUX + half8;
    const float* KAp = ka + ((size_t)b * SEQ + m0 + wn * 64 + r31) * DAUX + half8;
#pragma unroll
    for (int k0 = 0; k0 < 64; k0 += 16) {
      f16x8 qaf[2], kaf[2];
#pragma unroll
      for (int i2 = 0; i2 < 2; ++i2) {
        const float* p = QAp + (size_t)i2 * 32 * DAUX + k0;
        float4 u0 = *(const float4*)p, u1 = *(const float4*)(p + 4);
        qaf[i2] = f16x8{(f16)u0.x, (f16)u0.y, (f16)u0.z, (f16)u0.w,
                        (f16)u1.x, (f16)u1.y, (f16)u1.z, (f16)u1.w};
        const float* p2 = KAp + (size_t)i2 * 32 * DAUX + k0;
        float4 w0 = *(const float4*)p2, w1 = *(const float4*)(p2 + 4);
        kaf[i2] = f16x8{(f16)w0.x, (f16)w0.y, (f16)w0.z, (f16)w0.w,
                        (f16)w1.x, (f16)w1.y, (f16)w1.z, (f16)w1.w};
      }
#pragma unroll
      for (int jt = 0; jt < 2; ++jt)
#pragma unroll
        for (int it = 0; it < 2; ++it)
          aacc[it][jt] = MFMA32(qaf[it], kaf[jt], aacc[it][jt]);
    }
#pragma unroll
    for (int it = 0; it < 2; ++it)
#pragma unroll
      for (int jt = 0; jt < 2; ++jt)
#pragma unroll
        for (int r = 0; r < 16; ++r)
          sax2[it][jt][r >> 1][r & 1] = (f16)aacc[it][jt][r];
  }

  // ---- main QK^T, K=512, all-register 3-pass ----
  fx16 acc[2][2] = {};
  const size_t arow = (size_t)b * SEQ + n0 + wm * 64 + r31;
  const size_t brow = (size_t)b * SEQ + m0 + wn * 64 + r31;
  gemm3_regs(qh + arow * DM + half8, ql + arow * DM + half8,
             kh + brow * DM + half8, kl + brow * DM + half8, acc);

  // ---- merge + mask + f16 store ----
  const float mc = *mc_p, thr = *thr_p;
  const float invC = 1.0f / (1024.0f * 22.62741699796952f);  // /(32*32)/sqrt(512)
#pragma unroll
  for (int it = 0; it < 2; ++it)
#pragma unroll
    for (int jt = 0; jt < 2; ++jt) {
      int col = m0 + wn * 64 + jt * 32 + r31;
#pragma unroll
      for (int r = 0; r < 16; ++r) {
        int row = n0 + wm * 64 + it * 32 + (r & 3) + 8 * (r >> 2) + 4 * half;
        size_t rbase = ((size_t)b * SEQ + row) * SEQ;
        float s = acc[it][jt][r] * invC;
        float sa = (float)sax2[it][jt][r >> 1][r & 1] * 0.125f;
        if (sa != 0.0f && s > thr) s = (1.0f - mc) * s + mc * sa;
        if (adj[rbase + col] == 0) s = -65504.0f;   // f16 min -> exp()==0
        S16[rbase + col] = (f16)s;
      }
    }
}

// ---------------------------------------------------------------------------
// Softmax: one WAVE per row (4 rows/block, no barriers). In-place S16 row ->
// P16 = 1024*exp(s-max); rowsum = sum of the ROUNDED P16 (exact normalization).
// ---------------------------------------------------------------------------
__global__ __launch_bounds__(256) void softmax_p(
    f16* __restrict__ S16, float* __restrict__ rowsum) {
  const int wv = threadIdx.x >> 6, ln = threadIdx.x & 63;
  const size_t row = (size_t)blockIdx.x * 4 + wv;
  f16* Sr = S16 + row * SEQ;
  f16x8 v[4];
  float vals[32];
#pragma unroll
  for (int j = 0; j < 4; ++j) {
    v[j] = *(const f16x8*)(Sr + j * 512 + ln * 8);
#pragma unroll
    for (int i = 0; i < 8; ++i) vals[j * 8 + i] = (float)v[j][i];
  }
  float m = vals[0];
#pragma unroll
  for (int i = 1; i < 32; ++i) m = fmaxf(m, vals[i]);
#pragma unroll
  for (int off = 1; off < 64; off <<= 1) m = fmaxf(m, __shfl_xor(m, off, 64));
  float z = 0.f;
  f16x8 p16[4];
#pragma unroll
  for (int j = 0; j < 4; ++j)
#pragma unroll
    for (int i = 0; i < 8; ++i) {
      f16 p = (f16)(__expf(vals[j * 8 + i] - m) * 1024.0f);
      p16[j][i] = p;
      z += (float)p;
    }
#pragma unroll
  for (int off = 1; off < 64; off <<= 1) z += __shfl_xor(z, off, 64);
  if (ln == 0) rowsum[row] = z;
#pragma unroll
  for (int j = 0; j < 4; ++j)
    *(f16x8*)(Sr + j * 512 + ln * 8) = p16[j];
}

// ---------------------------------------------------------------------------
// PV (1-pass): O[n][d] = (sum_m P16[n][m]*vt[d][m])/rowsum[n]. All-register.
// ---------------------------------------------------------------------------
__global__ __launch_bounds__(256, 2) void pv_mfma(
    const f16* __restrict__ P16, const f16* __restrict__ vt,
    const float* __restrict__ rowsum, float* __restrict__ O) {
  const int t = threadIdx.x;
  const int n0 = blockIdx.x * 128, d0 = blockIdx.y * 128, b = blockIdx.z;
  const int lane = t & 63, wave = t >> 6;
  const int wm = wave >> 1, wn = wave & 1;
  const int r31 = lane & 31, half = lane >> 5;
  const int half8 = half * 8;
  fx16 acc[2][2] = {};
  const f16* Ap = P16 + ((size_t)b * SEQ + n0 + wm * 64 + r31) * SEQ + half8;
  const f16* Bp = vt + ((size_t)b * DM + d0 + wn * 64 + r31) * SEQ + half8;
  gemm1_regs<32, SEQ, SEQ>(Ap, Bp, acc);
#pragma unroll
  for (int it = 0; it < 2; ++it)
#pragma unroll
    for (int jt = 0; jt < 2; ++jt) {
      int d = d0 + wn * 64 + jt * 32 + r31;
#pragma unroll
      for (int r = 0; r < 16; ++r) {
        int n = n0 + wm * 64 + it * 32 + (r & 3) + 8 * (r >> 2) + 4 * half;
        float inv = 1.0f / rowsum[(size_t)b * SEQ + n];
        O[((size_t)b * SEQ + n) * DM + d] = acc[it][jt][r] * inv;
      }
    }
}

// ---------------------------------------------------------------------------
extern "C" void kernel_launch(void* const* d_in, const int* in_sizes, int n_in,
                              void* d_out, int out_size, void* d_ws, size_t ws_size,
                              hipStream_t stream) {
  const float* x   = (const float*)d_in[0];
  const float* qa  = (const float*)d_in[1];
  const float* ka  = (const float*)d_in[2];
  const int*   adj = (const int*)d_in[3];
  const float* mc  = (const float*)d_in[4];
  const float* Wq  = (const float*)d_in[5];
  const float* bq  = (const float*)d_in[6];
  const float* Wk  = (const float*)d_in[7];
  const float* bk  = (const float*)d_in[8];
  const float* Wv  = (const float*)d_in[9];
  const float* bv  = (const float*)d_in[10];
  const float* thr = (const float*)d_in[11];
  float* out = (float*)d_out;

  // ws layout (f16 elems): qh|ql|kh|kl|vt (8.39M each) | S16 (33.55M) | rowsum
  // convert outputs xh/xl/Wh/Wl alias the S16 region (dead before S16 written).
  f16* qh  = (f16*)d_ws;
  f16* ql  = qh + 8388608;
  f16* kh  = ql + 8388608;
  f16* kl  = kh + 8388608;
  f16* vt  = kl + 8388608;
  f16* S16 = vt + 8388608;
  float* rowsum = (float*)(S16 + 33554432);
  f16* xh = S16;                 // alias
  f16* xl = xh + 8388608;
  f16* Wh = xl + 8388608;        // [3][512*512]
  f16* Wl = Wh + 786432;

  convert_split<<<8960, 256, 0, stream>>>(x, Wq, Wk, Wv, xh, xl, Wh, Wl);
  qkv_mfma<<<dim3(128, 4, 3), 256, 0, stream>>>(xh, xl, Wh, Wl, bq, bk, bv,
                                                qh, ql, kh, kl, vt);
  scores_mfma<<<dim3(16, 16, 8), 256, 0, stream>>>(qh, ql, kh, kl, qa, ka, adj,
                                                   mc, thr, S16);
  softmax_p<<<4096, 256, 0, stream>>>(S16, rowsum);
  pv_mfma<<<dim3(16, 4, 8), 256, 0, stream>>>(S16, vt, rowsum, out);
}

// Round 9
// 504.497 us; speedup vs baseline: 1.6706x; 1.6706x over previous
//
#include <hip/hip_runtime.h>
#include <cstdint>

#define SEQ    2048
#define DM     512
#define DAUX   64

typedef _Float16 f16;
typedef __attribute__((ext_vector_type(2))) _Float16 f16x2;
typedef __attribute__((ext_vector_type(4))) _Float16 f16x4;
typedef __attribute__((ext_vector_type(8))) _Float16 f16x8;
typedef __attribute__((ext_vector_type(16))) float fx16;

#define MFMA32(a, b, c) __builtin_amdgcn_mfma_f32_32x32x16_f16(a, b, c, 0, 0, 0)

// async global->LDS, 16B per lane. LDS dest must be wave-uniform base + lane*16.
__device__ __forceinline__ void g2l16(const void* g, void* l) {
  __builtin_amdgcn_global_load_lds(
      (__attribute__((address_space(1))) void*)const_cast<void*>(g),
      (__attribute__((address_space(3))) void*)l, 16, 0, 0);
}

// ---- BK=32 tile [128][32], XOR swizzle on 8-elem blocks (jp ^ (row>>1)&3).
__device__ __forceinline__ void stage32(const f16* __restrict__ g0, int stride,
                                        f16* lds, int t) {
#pragma unroll
  for (int p = 0; p < 2; ++p) {
    int L = p * 256 + t;          // 0..511
    int row = L >> 2;             // 0..127
    int jp = L & 3;
    int jl = jp ^ ((row >> 1) & 3);
    g2l16(g0 + (size_t)row * stride + jl * 8, lds + L * 8);
  }
}
__device__ __forceinline__ f16x8 frag32(const f16* lds, int row, int kq) {
  int jp = (kq >> 3) ^ ((row >> 1) & 3);
  return *(const f16x8*)(lds + row * 32 + jp * 8);
}

// ---- BK=64 tile [128][64], swizzle jp ^ (row&7) (measured conflict-free, R4).
__device__ __forceinline__ void stage64(const f16* __restrict__ g0, int stride,
                                        f16* lds, int t) {
#pragma unroll
  for (int p = 0; p < 4; ++p) {
    int L = p * 256 + t;          // 0..1023
    int row = L >> 3;
    int jp = L & 7;
    int jl = jp ^ (row & 7);
    g2l16(g0 + (size_t)row * stride + jl * 8, lds + L * 8);
  }
}
__device__ __forceinline__ f16x8 frag64(const f16* lds, int row, int kq) {
  int jp = (kq >> 3) ^ (row & 7);
  return *(const f16x8*)(lds + row * 64 + jp * 8);
}

// ---- 32x32x16 MFMA. Wave tile 64x64 = 2x2 of 32x32.
// 3-pass split chunk on one 32KB buffer: Ah=buf, Al=+4096, Bh=+8192, Bl=+12288.
__device__ __forceinline__ void chunk3_32(const f16* buf,
                                          fx16 acc[2][2], int wm, int wn, int lane) {
  const f16* Ah = buf;
  const f16* Al = buf + 4096;
  const f16* Bh = buf + 8192;
  const f16* Bl = buf + 12288;
  const int r31 = lane & 31;
  const int kq = (lane >> 5) * 8;
#pragma unroll
  for (int k0 = 0; k0 < 32; k0 += 16) {
    f16x8 ah[2], al[2];
#pragma unroll
    for (int it = 0; it < 2; ++it) {
      int row = wm * 64 + it * 32 + r31;
      ah[it] = frag32(Ah, row, k0 + kq);
      al[it] = frag32(Al, row, k0 + kq);
    }
#pragma unroll
    for (int jt = 0; jt < 2; ++jt) {
      int col = wn * 64 + jt * 32 + r31;
      f16x8 bh = frag32(Bh, col, k0 + kq);
      f16x8 bl = frag32(Bl, col, k0 + kq);
#pragma unroll
      for (int it = 0; it < 2; ++it) {
        acc[it][jt] = MFMA32(ah[it], bh, acc[it][jt]);
        acc[it][jt] = MFMA32(ah[it], bl, acc[it][jt]);
        acc[it][jt] = MFMA32(al[it], bh, acc[it][jt]);
      }
    }
  }
}

// 1-pass chunk, BK=64, buffer holds A at 0 and B at +8192.
__device__ __forceinline__ void chunk1_64(const f16* buf,
                                          fx16 acc[2][2], int wm, int wn, int lane) {
  const f16* A = buf;
  const f16* B = buf + 8192;
  const int r31 = lane & 31;
  const int kq = (lane >> 5) * 8;
#pragma unroll
  for (int k0 = 0; k0 < 64; k0 += 16) {
    f16x8 a[2];
#pragma unroll
    for (int it = 0; it < 2; ++it)
      a[it] = frag64(A, wm * 64 + it * 32 + r31, k0 + kq);
#pragma unroll
    for (int jt = 0; jt < 2; ++jt) {
      f16x8 b = frag64(B, wn * 64 + jt * 32 + r31, k0 + kq);
#pragma unroll
      for (int it = 0; it < 2; ++it)
        acc[it][jt] = MFMA32(a[it], b, acc[it][jt]);
    }
  }
}

// ---------------------------------------------------------------------------
__global__ __launch_bounds__(256) void convert_split(
    const float* __restrict__ x, const float* __restrict__ Wq,
    const float* __restrict__ Wk, const float* __restrict__ Wv,
    f16* __restrict__ xh, f16* __restrict__ xl,
    f16* __restrict__ Wh, f16* __restrict__ Wl) {
  int idx = blockIdx.x * 256 + threadIdx.x;   // float4 index, 0..2293759
  const float* src; f16* dh; f16* dl; size_t off;
  if (idx < 2097152) { src = x; off = (size_t)idx; dh = xh; dl = xl; }
  else {
    int rr = idx - 2097152;
    int w = rr >> 16, o = rr & 65535;
    src = (w == 0) ? Wq : (w == 1) ? Wk : Wv;
    off = (size_t)o;
    dh = Wh + (size_t)w * 262144; dl = Wl + (size_t)w * 262144;
  }
  float4 v = ((const float4*)src)[off];
  float vv[4] = {v.x, v.y, v.z, v.w};
  f16x4 hv, lv;
#pragma unroll
  for (int i = 0; i < 4; ++i) {
    float s = vv[i] * 32.0f;
    f16 hi = (f16)s;
    hv[i] = hi;
    lv[i] = (f16)(s - (float)hi);
  }
  *(f16x4*)(dh + off * 4) = hv;
  *(f16x4*)(dl + off * 4) = lv;
}

// ---------------------------------------------------------------------------
// QKV with AA-disjoint double-buffer (two distinct __shared__ arrays).
// ---------------------------------------------------------------------------
__global__ __launch_bounds__(256) void qkv_mfma(
    const f16* __restrict__ xh, const f16* __restrict__ xl,
    const f16* __restrict__ Wh, const f16* __restrict__ Wl,
    const float* __restrict__ bq, const float* __restrict__ bk, const float* __restrict__ bv,
    f16* __restrict__ qh, f16* __restrict__ ql,
    f16* __restrict__ kh, f16* __restrict__ kl,
    f16* __restrict__ vt) {
  __shared__ __align__(16) f16 smA[16384];
  __shared__ __align__(16) f16 smB[16384];
  const int t = threadIdx.x;
  const int i0 = blockIdx.x * 128, j0 = blockIdx.y * 128, z = blockIdx.z;
  const f16* WhZ = Wh + (size_t)z * 262144;
  const f16* WlZ = Wl + (size_t)z * 262144;
  const int lane = t & 63, wave = t >> 6;
  const int wm = wave >> 1, wn = wave & 1;
  const int r31 = lane & 31, half = lane >> 5;
  fx16 acc[2][2] = {};
  const f16* xhB = xh + (size_t)i0 * DM;
  const f16* xlB = xl + (size_t)i0 * DM;
  const f16* WhB = WhZ + (size_t)j0 * DM;
  const f16* WlB = WlZ + (size_t)j0 * DM;
  if (z < 2) {
    stage32(xhB, DM, smA, t);
    stage32(xlB, DM, smA + 4096, t);
    stage32(WhB, DM, smA + 8192, t);
    stage32(WlB, DM, smA + 12288, t);
    __syncthreads();
#pragma unroll
    for (int cc = 0; cc < 16; cc += 2) {
      if (cc + 1 < 16) {
        int d0 = (cc + 1) * 32;
        stage32(xhB + d0, DM, smB, t);
        stage32(xlB + d0, DM, smB + 4096, t);
        stage32(WhB + d0, DM, smB + 8192, t);
        stage32(WlB + d0, DM, smB + 12288, t);
      }
      chunk3_32(smA, acc, wm, wn, lane);
      __syncthreads();
      if (cc + 2 < 16) {
        int d0 = (cc + 2) * 32;
        stage32(xhB + d0, DM, smA, t);
        stage32(xlB + d0, DM, smA + 4096, t);
        stage32(WhB + d0, DM, smA + 8192, t);
        stage32(WlB + d0, DM, smA + 12288, t);
      }
      chunk3_32(smB, acc, wm, wn, lane);
      if (cc + 2 < 16) __syncthreads();
    }
  } else {
    stage64(xhB, DM, smA, t);
    stage64(WhB, DM, smA + 8192, t);
    __syncthreads();
#pragma unroll
    for (int cc = 0; cc < 8; cc += 2) {
      if (cc + 1 < 8) {
        int d0 = (cc + 1) * 64;
        stage64(xhB + d0, DM, smB, t);
        stage64(WhB + d0, DM, smB + 8192, t);
      }
      chunk1_64(smA, acc, wm, wn, lane);
      __syncthreads();
      if (cc + 2 < 8) {
        int d0 = (cc + 2) * 64;
        stage64(xhB + d0, DM, smA, t);
        stage64(WhB + d0, DM, smA + 8192, t);
      }
      chunk1_64(smB, acc, wm, wn, lane);
      if (cc + 2 < 8) __syncthreads();
    }
  }
  const float* bias = (z == 0) ? bq : (z == 1) ? bk : bv;
  if (z < 2) {
    f16* oh = z ? kh : qh;  f16* ol = z ? kl : ql;
#pragma unroll
    for (int it = 0; it < 2; ++it)
#pragma unroll
      for (int jt = 0; jt < 2; ++jt) {
        int j = j0 + wn * 64 + jt * 32 + r31;
        float bj = bias[j];
#pragma unroll
        for (int r = 0; r < 16; ++r) {
          int ib = i0 + wm * 64 + it * 32 + (r & 3) + 8 * (r >> 2) + 4 * half;
          float val = acc[it][jt][r] * (1.0f / 1024.0f) + bj;
          float s = val * 32.0f;
          f16 hi = (f16)s;
          oh[(size_t)ib * DM + j] = hi;
          ol[(size_t)ib * DM + j] = (f16)(s - (float)hi);
        }
      }
  } else {
#pragma unroll
    for (int it = 0; it < 2; ++it)
#pragma unroll
      for (int jt = 0; jt < 2; ++jt) {
        int j = j0 + wn * 64 + jt * 32 + r31;
        float bj = bias[j];
#pragma unroll
        for (int q4 = 0; q4 < 4; ++q4) {
          int ib = i0 + wm * 64 + it * 32 + 8 * q4 + 4 * half;
          int bb = ib >> 11, nb = ib & 2047;
          f16x4 hv;
#pragma unroll
          for (int g = 0; g < 4; ++g)
            hv[g] = (f16)(acc[it][jt][q4 * 4 + g] * (1.0f / 1024.0f) + bj);
          *(f16x4*)(vt + ((size_t)(bb * DM + j)) * SEQ + nb) = hv;
        }
      }
  }
}

// ---------------------------------------------------------------------------
// Scores with AA-disjoint double-buffer; aux first (overlaps chunk-0 prefetch).
// ---------------------------------------------------------------------------
__global__ __launch_bounds__(256) void scores_mfma(
    const f16* __restrict__ qh, const f16* __restrict__ ql,
    const f16* __restrict__ kh, const f16* __restrict__ kl,
    const float* __restrict__ qa, const float* __restrict__ ka,
    const int* __restrict__ adj,
    const float* __restrict__ mc_p, const float* __restrict__ thr_p,
    f16* __restrict__ S16) {
  __shared__ __align__(16) f16 smA[16384];
  __shared__ __align__(16) f16 smB[16384];
  const int t = threadIdx.x;
  const int n0 = blockIdx.x * 128, m0 = blockIdx.y * 128, b = blockIdx.z;
  const int lane = t & 63, wave = t >> 6;
  const int wm = wave >> 1, wn = wave & 1;
  const int r31 = lane & 31, half = lane >> 5;
  const int kq = half * 8;

  const f16* qhB = qh + ((size_t)b * SEQ + n0) * DM;
  const f16* qlB = ql + ((size_t)b * SEQ + n0) * DM;
  const f16* khB = kh + ((size_t)b * SEQ + m0) * DM;
  const f16* klB = kl + ((size_t)b * SEQ + m0) * DM;

  // chunk-0 prefetch into smA (async; hides behind aux phase)
  stage32(qhB, DM, smA, t);
  stage32(qlB, DM, smA + 4096, t);
  stage32(khB, DM, smA + 8192, t);
  stage32(klB, DM, smA + 12288, t);

  // aux tiles into smB via plain stores
  f16* QAl = smB;
  f16* KAl = smB + 8192;
  const float* QAb = qa + ((size_t)b * SEQ + n0) * DAUX;
  const float* KAb = ka + ((size_t)b * SEQ + m0) * DAUX;
#pragma unroll
  for (int p = 0; p < 4; ++p) {
    int L8 = p * 256 + t;
    int row = L8 >> 3, jb = L8 & 7;
    int c8 = jb * 8;
    int jp = jb ^ (row & 7);
    float4 u0 = *(const float4*)(QAb + (size_t)row * DAUX + c8);
    float4 u1 = *(const float4*)(QAb + (size_t)row * DAUX + c8 + 4);
    f16x8 hq = {(f16)u0.x,(f16)u0.y,(f16)u0.z,(f16)u0.w,(f16)u1.x,(f16)u1.y,(f16)u1.z,(f16)u1.w};
    *(f16x8*)(QAl + row * 64 + jp * 8) = hq;
    float4 w0 = *(const float4*)(KAb + (size_t)row * DAUX + c8);
    float4 w1 = *(const float4*)(KAb + (size_t)row * DAUX + c8 + 4);
    f16x8 hk = {(f16)w0.x,(f16)w0.y,(f16)w0.z,(f16)w0.w,(f16)w1.x,(f16)w1.y,(f16)w1.z,(f16)w1.w};
    *(f16x8*)(KAl + row * 64 + jp * 8) = hk;
  }
  __syncthreads();

  // aux MFMA (reads smB)
  f16x2 sax2[2][2][8];
  {
    fx16 aacc[2][2] = {};
#pragma unroll
    for (int k0 = 0; k0 < 64; k0 += 16) {
      f16x8 qaf[2];
#pragma unroll
      for (int it = 0; it < 2; ++it)
        qaf[it] = frag64(QAl, wm * 64 + it * 32 + r31, k0 + kq);
#pragma unroll
      for (int jt = 0; jt < 2; ++jt) {
        f16x8 kaf = frag64(KAl, wn * 64 + jt * 32 + r31, k0 + kq);
#pragma unroll
        for (int it = 0; it < 2; ++it)
          aacc[it][jt] = MFMA32(qaf[it], kaf, aacc[it][jt]);
      }
    }
#pragma unroll
    for (int it = 0; it < 2; ++it)
#pragma unroll
      for (int jt = 0; jt < 2; ++jt)
#pragma unroll
        for (int r = 0; r < 16; ++r)
          sax2[it][jt][r >> 1][r & 1] = (f16)aacc[it][jt][r];
  }
  __syncthreads();   // aux reads done before smB is re-staged

  // main QK^T: even chunks -> smA, odd -> smB, one barrier per chunk
  fx16 acc[2][2] = {};
#pragma unroll
  for (int cc = 0; cc < 16; cc += 2) {
    if (cc + 1 < 16) {
      int d0 = (cc + 1) * 32;
      stage32(qhB + d0, DM, smB, t);
      stage32(qlB + d0, DM, smB + 4096, t);
      stage32(khB + d0, DM, smB + 8192, t);
      stage32(klB + d0, DM, smB + 12288, t);
    }
    chunk3_32(smA, acc, wm, wn, lane);
    __syncthreads();
    if (cc + 2 < 16) {
      int d0 = (cc + 2) * 32;
      stage32(qhB + d0, DM, smA, t);
      stage32(qlB + d0, DM, smA + 4096, t);
      stage32(khB + d0, DM, smA + 8192, t);
      stage32(klB + d0, DM, smA + 12288, t);
    }
    chunk3_32(smB, acc, wm, wn, lane);
    if (cc + 2 < 16) __syncthreads();
  }

  // merge + mask + f16 store
  const float mc = *mc_p, thr = *thr_p;
  const float invC = 1.0f / (1024.0f * 22.62741699796952f);
#pragma unroll
  for (int it = 0; it < 2; ++it)
#pragma unroll
    for (int jt = 0; jt < 2; ++jt) {
      int col = m0 + wn * 64 + jt * 32 + r31;
#pragma unroll
      for (int r = 0; r < 16; ++r) {
        int row = n0 + wm * 64 + it * 32 + (r & 3) + 8 * (r >> 2) + 4 * half;
        size_t rbase = ((size_t)b * SEQ + row) * SEQ;
        float s = acc[it][jt][r] * invC;
        float sa = (float)sax2[it][jt][r >> 1][r & 1] * 0.125f;
        if (sa != 0.0f && s > thr) s = (1.0f - mc) * s + mc * sa;
        if (adj[rbase + col] == 0) s = -65504.0f;
        S16[rbase + col] = (f16)s;
      }
    }
}

// ---------------------------------------------------------------------------
__global__ __launch_bounds__(256) void softmax_p(
    f16* __restrict__ S16, float* __restrict__ rowsum) {
  const int wv = threadIdx.x >> 6, ln = threadIdx.x & 63;
  const size_t row = (size_t)blockIdx.x * 4 + wv;
  f16* Sr = S16 + row * SEQ;
  f16x8 v[4];
  float vals[32];
#pragma unroll
  for (int j = 0; j < 4; ++j) {
    v[j] = *(const f16x8*)(Sr + j * 512 + ln * 8);
#pragma unroll
    for (int i = 0; i < 8; ++i) vals[j * 8 + i] = (float)v[j][i];
  }
  float m = vals[0];
#pragma unroll
  for (int i = 1; i < 32; ++i) m = fmaxf(m, vals[i]);
#pragma unroll
  for (int off = 1; off < 64; off <<= 1) m = fmaxf(m, __shfl_xor(m, off, 64));
  float z = 0.f;
  f16x8 p16[4];
#pragma unroll
  for (int j = 0; j < 4; ++j)
#pragma unroll
    for (int i = 0; i < 8; ++i) {
      f16 p = (f16)(__expf(vals[j * 8 + i] - m) * 1024.0f);
      p16[j][i] = p;
      z += (float)p;
    }
#pragma unroll
  for (int off = 1; off < 64; off <<= 1) z += __shfl_xor(z, off, 64);
  if (ln == 0) rowsum[row] = z;
#pragma unroll
  for (int j = 0; j < 4; ++j)
    *(f16x8*)(Sr + j * 512 + ln * 8) = p16[j];
}

// ---------------------------------------------------------------------------
__global__ __launch_bounds__(256) void pv_mfma(
    const f16* __restrict__ P16, const f16* __restrict__ vt,
    const float* __restrict__ rowsum, float* __restrict__ O) {
  __shared__ __align__(16) f16 smA[16384];
  __shared__ __align__(16) f16 smB[16384];
  const int t = threadIdx.x;
  const int n0 = blockIdx.x * 128, d0 = blockIdx.y * 128, b = blockIdx.z;
  const int lane = t & 63, wave = t >> 6;
  const int wm = wave >> 1, wn = wave & 1;
  const int r31 = lane & 31, half = lane >> 5;
  fx16 acc[2][2] = {};
  const f16* Pb = P16 + ((size_t)b * SEQ + n0) * SEQ;
  const f16* Vb = vt + ((size_t)b * DM + d0) * SEQ;
  stage64(Pb, SEQ, smA, t);
  stage64(Vb, SEQ, smA + 8192, t);
  __syncthreads();
#pragma unroll
  for (int cc = 0; cc < 32; cc += 2) {
    if (cc + 1 < 32) {
      int m0 = (cc + 1) * 64;
      stage64(Pb + m0, SEQ, smB, t);
      stage64(Vb + m0, SEQ, smB + 8192, t);
    }
    chunk1_64(smA, acc, wm, wn, lane);
    __syncthreads();
    if (cc + 2 < 32) {
      int m0 = (cc + 2) * 64;
      stage64(Pb + m0, SEQ, smA, t);
      stage64(Vb + m0, SEQ, smA + 8192, t);
    }
    chunk1_64(smB, acc, wm, wn, lane);
    if (cc + 2 < 32) __syncthreads();
  }
#pragma unroll
  for (int it = 0; it < 2; ++it)
#pragma unroll
    for (int jt = 0; jt < 2; ++jt) {
      int d = d0 + wn * 64 + jt * 32 + r31;
#pragma unroll
      for (int r = 0; r < 16; ++r) {
        int n = n0 + wm * 64 + it * 32 + (r & 3) + 8 * (r >> 2) + 4 * half;
        float inv = 1.0f / rowsum[(size_t)b * SEQ + n];
        O[((size_t)b * SEQ + n) * DM + d] = acc[it][jt][r] * inv;
      }
    }
}

// ---------------------------------------------------------------------------
extern "C" void kernel_launch(void* const* d_in, const int* in_sizes, int n_in,
                              void* d_out, int out_size, void* d_ws, size_t ws_size,
                              hipStream_t stream) {
  const float* x   = (const float*)d_in[0];
  const float* qa  = (const float*)d_in[1];
  const float* ka  = (const float*)d_in[2];
  const int*   adj = (const int*)d_in[3];
  const float* mc  = (const float*)d_in[4];
  const float* Wq  = (const float*)d_in[5];
  const float* bq  = (const float*)d_in[6];
  const float* Wk  = (const float*)d_in[7];
  const float* bk  = (const float*)d_in[8];
  const float* Wv  = (const float*)d_in[9];
  const float* bv  = (const float*)d_in[10];
  const float* thr = (const float*)d_in[11];
  float* out = (float*)d_out;

  f16* qh  = (f16*)d_ws;
  f16* ql  = qh + 8388608;
  f16* kh  = ql + 8388608;
  f16* kl  = kh + 8388608;
  f16* vt  = kl + 8388608;
  f16* S16 = vt + 8388608;
  float* rowsum = (float*)(S16 + 33554432);
  f16* xh = S16;                 // alias (dead before S16 written)
  f16* xl = xh + 8388608;
  f16* Wh = xl + 8388608;
  f16* Wl = Wh + 786432;

  convert_split<<<8960, 256, 0, stream>>>(x, Wq, Wk, Wv, xh, xl, Wh, Wl);
  qkv_mfma<<<dim3(128, 4, 3), 256, 0, stream>>>(xh, xl, Wh, Wl, bq, bk, bv,
                                                qh, ql, kh, kl, vt);
  scores_mfma<<<dim3(16, 16, 8), 256, 0, stream>>>(qh, ql, kh, kl, qa, ka, adj,
                                                   mc, thr, S16);
  softmax_p<<<4096, 256, 0, stream>>>(S16, rowsum);
  pv_mfma<<<dim3(16, 4, 8), 256, 0, stream>>>(S16, vt, rowsum, out);
}